// Round 6
// baseline (240.749 us; speedup 1.0000x reference)
//
#include <hip/hip_runtime.h>

#define LR 0.01f
#define EPS 1e-10f

typedef float f32x4 __attribute__((ext_vector_type(4)));

// Inputs: idx (N, int32), grad (N,64 f32), state (V,64 f32), emb (V,64 f32)
// Outputs concatenated: new_state (V*64 f32) then new_emb (V*64 f32)
// Scratch: head[V] int32 (4 MB) + next[N] int32 (1 MB) in d_ws
//
// Chain-gather strategy (R3):
//  - head init via hipMemsetAsync(0xFF) == -1
//  - link pass: next[i] = atomicExch(&head[idx[i]], i)  (int atomics, L2-hot)
//  - one fused streaming pass over V rows: walk chain (0 iters if untouched),
//    mean, Adagrad update; untouched rows are the exact c==0 special case.
// R6: plain loads/stores (NT hint measured -5us worse), 2 float4s per thread
// (8 threads/row: half the head broadcasts, 2x MLP per stream), 32-bit task
// indices.

__global__ void link_kernel(const int* __restrict__ idx,
                            int* __restrict__ head,
                            int* __restrict__ next, int N) {
    int i = blockIdx.x * blockDim.x + threadIdx.x;
    if (i >= N) return;
    next[i] = atomicExch(&head[idx[i]], i);
}

// 8 threads per vocab row; each handles 2 consecutive float4s (32 B) per stream.
__global__ void fused_kernel(const float* __restrict__ state,
                             const float* __restrict__ emb,
                             const float* __restrict__ grad,
                             const int* __restrict__ head,
                             const int* __restrict__ next,
                             float* __restrict__ out_state,
                             float* __restrict__ out_emb, int total8) {
    int stride = gridDim.x * blockDim.x;
    for (int u = blockIdx.x * blockDim.x + threadIdx.x; u < total8; u += stride) {
        int row = u >> 3;
        int q = u & 7;
        size_t off = (size_t)row * 64 + (size_t)q * 8;   // elements

        int h = head[row];
        f32x4 sA = *reinterpret_cast<const f32x4*>(state + off);
        f32x4 sB = *reinterpret_cast<const f32x4*>(state + off + 4);
        f32x4 eA = *reinterpret_cast<const f32x4*>(emb + off);
        f32x4 eB = *reinterpret_cast<const f32x4*>(emb + off + 4);

        // gather grad rows along the chain (0 iterations for untouched rows)
        f32x4 sumA = {0.f, 0.f, 0.f, 0.f};
        f32x4 sumB = {0.f, 0.f, 0.f, 0.f};
        int c = 0;
        for (int j = h; j >= 0; j = next[j]) {
            size_t goff = (size_t)j * 64 + (size_t)q * 8;
            sumA += *reinterpret_cast<const f32x4*>(grad + goff);
            sumB += *reinterpret_cast<const f32x4*>(grad + goff + 4);
            ++c;
        }
        // c==0: inv=0 -> mean=0 -> new_state==s, new_emb==e (exact)
        float inv = (c > 0) ? (1.0f / (float)c) : 0.0f;
        f32x4 mA = sumA * inv, mB = sumB * inv;
        f32x4 nsA = sA + mA * mA;
        f32x4 nsB = sB + mB * mB;
        f32x4 neA, neB;
        #pragma unroll
        for (int k = 0; k < 4; ++k) {
            neA[k] = eA[k] - LR * mA[k] / (sqrtf(nsA[k]) + EPS);
            neB[k] = eB[k] - LR * mB[k] / (sqrtf(nsB[k]) + EPS);
        }
        *reinterpret_cast<f32x4*>(out_state + off)     = nsA;
        *reinterpret_cast<f32x4*>(out_state + off + 4) = nsB;
        *reinterpret_cast<f32x4*>(out_emb + off)       = neA;
        *reinterpret_cast<f32x4*>(out_emb + off + 4)   = neB;
    }
}

extern "C" void kernel_launch(void* const* d_in, const int* in_sizes, int n_in,
                              void* d_out, int out_size, void* d_ws, size_t ws_size,
                              hipStream_t stream) {
    const int* idx = (const int*)d_in[0];
    const float* grad = (const float*)d_in[1];
    const float* state = (const float*)d_in[2];
    const float* emb = (const float*)d_in[3];

    int N = in_sizes[0];
    int D = in_sizes[1] / N;         // expected 64
    long long VD = in_sizes[2];
    int V = (int)(VD / D);

    float* out_state = (float*)d_out;
    float* out_emb = (float*)d_out + (size_t)V * D;
    int* head = (int*)d_ws;                    // V ints
    int* next = (int*)d_ws + V;                // N ints

    const int threads = 256;

    // 1. head = -1 via memset (graph-capture-safe async memset)
    (void)hipMemsetAsync(head, 0xFF, (size_t)V * sizeof(int), stream);

    // 2. build chains (int atomics on 4 MB L2-hot region)
    link_kernel<<<(N + threads - 1) / threads, threads, 0, stream>>>(idx, head, next, N);

    // 3. fused streaming pass: gather+update (or exact copy when c==0)
    {
        int total8 = V * 8;
        int blocks = 4096;
        fused_kernel<<<blocks, threads, 0, stream>>>(state, emb, grad, head, next,
                                                     out_state, out_emb, total8);
    }
}

// Round 7
// 215.438 us; speedup vs baseline: 1.1175x; 1.1175x over previous
//
#include <hip/hip_runtime.h>

#define LR 0.01f
#define EPS 1e-10f

typedef float f32x4 __attribute__((ext_vector_type(4)));

// Inputs: idx (N, int32), grad (N,64 f32), state (V,64 f32), emb (V,64 f32)
// Outputs concatenated: new_state (V*64 f32) then new_emb (V*64 f32)
// Scratch: head[V] int32 (4 MB) + next[N] int32 (1 MB) in d_ws
//
// Chain-gather strategy (R3, the measured best):
//  - head init via hipMemsetAsync(0xFF) == -1
//  - link pass: next[i] = atomicExch(&head[idx[i]], i)  (int atomics, L2-hot)
//  - one fused streaming pass, 16 threads per vocab row (one float4 each):
//    wave = 4 contiguous rows = 1 KB per load instruction (perfect coalescing).
//    Untouched rows are the exact c==0 special case of the update.
// Measured negatives (do not reintroduce): nontemporal hints (-5us),
// 8 threads/row with 2x float4 (stride-32B lanes, -21us), grid-stride 4096.
// R7: 32-bit offsets only (off = 4*t exactly).

__global__ void link_kernel(const int* __restrict__ idx,
                            int* __restrict__ head,
                            int* __restrict__ next, int N) {
    int i = blockIdx.x * blockDim.x + threadIdx.x;
    if (i >= N) return;
    next[i] = atomicExch(&head[idx[i]], i);
}

// 16 threads per vocab row (each handles one float4 of the 64-wide row).
__global__ void fused_kernel(const float* __restrict__ state,
                             const float* __restrict__ emb,
                             const float* __restrict__ grad,
                             const int* __restrict__ head,
                             const int* __restrict__ next,
                             float* __restrict__ out_state,
                             float* __restrict__ out_emb, int total) {
    int t = blockIdx.x * blockDim.x + threadIdx.x;   // over V*16, fits int
    if (t >= total) return;
    int row = t >> 4;
    int q = t & 15;
    unsigned off = (unsigned)t << 2;                 // == row*64 + q*4

    int h = head[row];
    f32x4 s = *reinterpret_cast<const f32x4*>(state + off);
    f32x4 e = *reinterpret_cast<const f32x4*>(emb + off);

    // gather grad rows along the chain (0 iterations for untouched rows)
    f32x4 sum = {0.f, 0.f, 0.f, 0.f};
    int c = 0;
    for (int j = h; j >= 0; j = next[j]) {
        sum += *reinterpret_cast<const f32x4*>(grad + ((unsigned)j << 6) + ((unsigned)q << 2));
        ++c;
    }
    // c==0: inv=0 -> mean=0 -> new_state==s, new_emb==e (exact)
    float inv = (c > 0) ? (1.0f / (float)c) : 0.0f;
    f32x4 m = sum * inv;
    f32x4 ns = s + m * m;
    f32x4 ne;
    #pragma unroll
    for (int k = 0; k < 4; ++k) {
        ne[k] = e[k] - LR * m[k] / (sqrtf(ns[k]) + EPS);
    }
    *reinterpret_cast<f32x4*>(out_state + off) = ns;
    *reinterpret_cast<f32x4*>(out_emb + off) = ne;
}

extern "C" void kernel_launch(void* const* d_in, const int* in_sizes, int n_in,
                              void* d_out, int out_size, void* d_ws, size_t ws_size,
                              hipStream_t stream) {
    const int* idx = (const int*)d_in[0];
    const float* grad = (const float*)d_in[1];
    const float* state = (const float*)d_in[2];
    const float* emb = (const float*)d_in[3];

    int N = in_sizes[0];
    int D = in_sizes[1] / N;         // expected 64
    long long VD = in_sizes[2];
    int V = (int)(VD / D);

    float* out_state = (float*)d_out;
    float* out_emb = (float*)d_out + (size_t)V * D;
    int* head = (int*)d_ws;                    // V ints
    int* next = (int*)d_ws + V;                // N ints

    const int threads = 256;

    // 1. head = -1 via memset (graph-capture-safe async memset)
    (void)hipMemsetAsync(head, 0xFF, (size_t)V * sizeof(int), stream);

    // 2. build chains (int atomics on 4 MB L2-hot region)
    link_kernel<<<(N + threads - 1) / threads, threads, 0, stream>>>(idx, head, next, N);

    // 3. fused streaming pass: gather+update (or exact copy when c==0)
    {
        int total = V * 16;
        int blocks = (total + threads - 1) / threads;
        fused_kernel<<<blocks, threads, 0, stream>>>(state, emb, grad, head, next,
                                                     out_state, out_emb, total);
    }
}